// Round 6
// baseline (77.638 us; speedup 1.0000x reference)
//
#include <hip/hip_runtime.h>

// ---------------- problem constants ----------------
#define NBLK   98304     // 8*3*64*64 total 8x8 blocks
#define NPB    12288     // blocks per batch (3*64*64)
#define HW     512
#define NUMBITS 4096
#define RANK0  29490     // floor(0.3*(NBLK-1))
#define RANK1  29491
#define STEGO_N 6291456  // 8*3*512*512
#define ELIG   111       // ceil(4096/37) blocks contain eligible coefficients
#define HIST   8192      // fixed bins over variance range [0, 0.25]
#define CCAP   2048
#define NWG    384       // k_stats workgroups

typedef unsigned long long ull;

// ---------------- DCT matrix as compile-time constants ----------------
struct DTab { double d[8][8]; };

constexpr double CT_[9] = {
  1.0,
  0.98078528040323044913,
  0.92387953251128675613,
  0.83146961230254523708,
  0.70710678118654752440,
  0.55557023301960222474,
  0.38268343236508977173,
  0.19509032201612826785,
  0.0
};
constexpr double cospi16(int m){           // cos(pi*m/16), m >= 0
  int r = m % 32;
  return (r<=8) ? CT_[r] : (r<=16) ? -CT_[16-r] : (r<=24) ? -CT_[r-16] : CT_[32-r];
}
constexpr DTab make_dtab(){
  DTab t{};
  for(int k=0;k<8;k++) for(int n=0;n<8;n++){
    double s = (k==0) ? 0.35355339059327376220 : 0.5; // sqrt(1/8), sqrt(2/8)
    t.d[k][n] = s * cospi16((2*n+1)*k);
  }
  return t;
}
constexpr DTab DT = make_dtab();

constexpr ull make_fmask(){ // bit u*8+v set iff 3 <= u+v <= 8
  ull m = 0;
  for(int u=0;u<8;u++) for(int v=0;v<8;v++){
    int s=u+v; if(s>=3 && s<=8) m |= (1ULL << (u*8+v));
  }
  return m;
}
constexpr ull FMASK = make_fmask();  // 37 bits set

__device__ __forceinline__ int binof(double v){
  int b = (int)(v * 32768.0);               // HIST/0.25 — fixed, deterministic
  if(b > HIST-1) b = HIST-1;
  return b;                                 // v >= 0 always
}

// ---------------- kernels ----------------

// fused: stego = cover (copy), map = 0, per-block fp64 variance,
// zero bins + candidate counter (no atomics here -> race-free self-zeroing)
__global__ __launch_bounds__(256) void k_stats(const float* __restrict__ cover,
    float* __restrict__ out, double* __restrict__ var,
    unsigned* __restrict__ bins, unsigned* __restrict__ cand_cnt){
  int tid = threadIdx.x;
  int i = blockIdx.x*256 + tid;             // block id over (b,c,n,m)
  if(i < HIST) bins[i] = 0u;
  if(i == HIST) *cand_cnt = 0u;
  int m = i & 63, n = (i>>6)&63, bc = i>>12;
  const float* p  = cover + ((size_t)bc*HW + (size_t)n*8)*HW + (size_t)m*8;
  float*       po = out   + ((size_t)bc*HW + (size_t)n*8)*HW + (size_t)m*8;
  double s1=0.0, s2=0.0;
#pragma unroll
  for(int r=0;r<8;r++){
    const float4* q = (const float4*)(p + (size_t)r*HW);
    float4 a = q[0], b = q[1];
    float4* w = (float4*)(po + (size_t)r*HW);
    w[0]=a; w[1]=b;
    double x;
    x=(double)a.x; s1+=x; s2+=x*x;
    x=(double)a.y; s1+=x; s2+=x*x;
    x=(double)a.z; s1+=x; s2+=x*x;
    x=(double)a.w; s1+=x; s2+=x*x;
    x=(double)b.x; s1+=x; s2+=x*x;
    x=(double)b.y; s1+=x; s2+=x*x;
    x=(double)b.z; s1+=x; s2+=x*x;
    x=(double)b.w; s1+=x; s2+=x*x;
  }
  double mean = s1*(1.0/64.0);
  double v = s2*(1.0/64.0) - mean*mean;
  if(v < 0.0) v = 0.0;
  var[i] = v;
  // zero the embedding map for this block (fixed up later for eligible blocks)
  float4 z = make_float4(0.f,0.f,0.f,0.f);
  float4* pm = (float4*)(out + (size_t)STEGO_N + (size_t)i*64);
#pragma unroll
  for(int j=0;j<16;j++) pm[j] = z;
}

// global-atomic histogram: one add per element, ~12 adds/bin -> no contention
__global__ __launch_bounds__(1024) void k_hist(const double* __restrict__ var,
    unsigned* __restrict__ bins){
  int i = blockIdx.x*1024 + threadIdx.x;
  atomicAdd(&bins[binof(var[i])], 1u);
}

// every WG redundantly locates the bins holding RANK0/RANK1 (+ count below b0)
// via an LDS scan of the 8192 global bins; then gathers its own slice's
// candidates into a global list (order-independent). WG0 publishes desc.
__global__ __launch_bounds__(1024) void k_gather(const double* __restrict__ var,
    const unsigned* __restrict__ bins, unsigned* __restrict__ cand_cnt,
    ull* __restrict__ cand, int* __restrict__ desc){
  __shared__ unsigned sscan[1024];
  __shared__ int sdesc[3];                  // b0, b1, Cb (count below b0)
  int tid = threadIdx.x;
  // per-thread sum of its 8 bins, then inclusive Hillis scan over 1024 threads
  int base = tid*8;
  unsigned bl[8];
  unsigned ls = 0;
#pragma unroll
  for(int k=0;k<8;k++){ bl[k]=bins[base+k]; ls += bl[k]; }
  sscan[tid]=ls; __syncthreads();
  for(int off=1;off<1024;off<<=1){
    unsigned add = (tid>=off)? sscan[tid-off] : 0u;
    __syncthreads();
    sscan[tid]+=add;
    __syncthreads();
  }
  unsigned incl = sscan[tid], excl = incl - ls;
  if((unsigned)RANK0 >= excl && (unsigned)RANK0 < incl){
    unsigned c = excl;
#pragma unroll
    for(int k=0;k<8;k++){
      if((unsigned)RANK0 < c+bl[k]){ sdesc[0]=base+k; sdesc[2]=(int)c; break; }
      c += bl[k];
    }
  }
  if((unsigned)RANK1 >= excl && (unsigned)RANK1 < incl){
    unsigned c = excl;
#pragma unroll
    for(int k=0;k<8;k++){
      if((unsigned)RANK1 < c+bl[k]){ sdesc[1]=base+k; break; }
      c += bl[k];
    }
  }
  __syncthreads();
  int b0=sdesc[0], b1=sdesc[1];
  if(blockIdx.x==0 && tid==0){ desc[0]=b0; desc[1]=b1; desc[2]=sdesc[2]; }
  // gather candidates from this WG's slice
  int i = blockIdx.x*1024 + tid;
  double v = var[i];
  int bn = binof(v);
  if(bn >= b0 && bn <= b1){
    unsigned idx = atomicAdd(cand_cnt, 1u);
    if(idx < CCAP) cand[idx] = (ull)__double_as_longlong(v);
  }
}

// ONE workgroup: exact rank select (K small) -> thr -> early-exit ballot scan
// -> 16-wave shuffle-DCT fp64 embed of <=111 blocks.
__global__ __launch_bounds__(1024) void k_final(const float* __restrict__ cover,
    const int* __restrict__ secret, const double* __restrict__ var,
    const int* __restrict__ desc, const unsigned* __restrict__ cand_cnt,
    const ull* __restrict__ gcand, float* __restrict__ out){
  __shared__ ull cand[CCAP];                // 16 KB
  __shared__ int queue[ELIG];
  __shared__ unsigned wcnt[16];
  __shared__ double sAB[2];
  int tid = threadIdx.x;
  unsigned Ku = *cand_cnt;
  int K = (Ku < (unsigned)CCAP) ? (int)Ku : CCAP;
  for(int t=tid;t<K;t+=1024) cand[t]=gcand[t];
  int Cb = desc[2];
  __syncthreads();
  // exact rank select among candidates (duplicates handled; order-independent)
  int r0 = RANK0 - Cb, r1 = RANK1 - Cb;
  for(int t=tid; t<K; t+=1024){
    ull x = cand[t];
    int cl=0, ce=0;
    for(int j2=0;j2<K;j2++){ ull y=cand[j2]; cl += (y<x); ce += (y==x); }
    if(cl<=r0 && r0<cl+ce) sAB[0]=__longlong_as_double((long long)x);
    if(cl<=r1 && r1<cl+ce) sAB[1]=__longlong_as_double((long long)x);
  }
  __syncthreads();
  double A=sAB[0], Bv=sAB[1];
  double thr = A + 0.9*(Bv - A);   // selection: var_norm>thr <=> var>thr_raw

  // --- chunked ballot scan in index order; stop once ELIG blocks queued ---
  int wid = tid>>6, lane = tid&63;
  int total = 0;
  for(int chunk=0; chunk<96; chunk++){
    int i = chunk*1024 + tid;
    int f = (var[i] > thr) ? 1 : 0;
    ull bal = __ballot(f);
    if(lane==0) wcnt[wid] = (unsigned)__popcll(bal);
    __syncthreads();
    int wpre=0, csum=0;
#pragma unroll
    for(int w=0;w<16;w++){
      int c = (int)wcnt[w];
      if(w<wid) wpre += c;
      csum += c;
    }
    int P = total + wpre + (int)__popcll(bal & ((1ULL<<lane)-1ULL));
    if(f && P < ELIG) queue[P] = i;   // P == global selected-rank, no atomics
    total += csum;
    __syncthreads();
    if(total >= ELIG) break;
  }
  int nq = (total < ELIG) ? total : ELIG;

  // --- embed: wave w handles queue[w], queue[w+16], ... (fp64 shuffle DCT) ---
  int lr = lane>>3, lc = lane&7;
  for(int q = wid; q < nq; q += 16){
    int bi = queue[q], S2 = q;
    int m = bi & 63, n = (bi>>6)&63, bc = bi>>12, bb = bi / NPB;
    const float* p  = cover + ((size_t)bc*HW + (size_t)n*8)*HW + (size_t)m*8;
    float*       po = out   + ((size_t)bc*HW + (size_t)n*8)*HW + (size_t)m*8;
    double x = (double)p[(size_t)lr*HW + lc];     // X[lr][lc]
    // stage1: T1[r][v] = sum_j X[r][j]*D[v][j]
    double t1 = 0.0;
#pragma unroll
    for(int j=0;j<8;j++) t1 += __shfl(x, lr*8+j) * DT.d[lc][j];
    // stage2: C[u][v] = sum_k D[u][k]*T1[k][v]
    double coef = 0.0;
#pragma unroll
    for(int k=0;k<8;k++) coef += DT.d[lr][k] * __shfl(t1, k*8+lc);
    // embedding
    bool sel = (FMASK>>lane)&1ULL;
    float mv = 0.f;
    if(sel){
      int fp  = (int)__popcll(FMASK & ((1ULL<<lane)-1ULL));
      int ord = 37*S2 + fp;
      if(ord < NUMBITS){
        mv = 1.f;
        double rnd = rint(coef);                  // round half-to-even == jnp.round
        int lsb = ((int)fabs(rnd)) & 1;
        int bit = secret[(size_t)bb*NUMBITS + ord];
        if(lsb != bit) coef += ((coef>=0.0)?1.0:-1.0)*(2.0*(double)bit-1.0)*0.5;
      }
    }
    out[(size_t)STEGO_N + (size_t)bi*64 + lane] = mv;
    // inv stage1: T2[r][v] = sum_u D[u][r]*M[u][v]
    double t2 = 0.0;
#pragma unroll
    for(int u=0;u<8;u++) t2 += DT.d[u][lr] * __shfl(coef, u*8+lc);
    // inv stage2: pix[r][k] = sum_q T2[r][q]*D[q][k]
    double px = 0.0;
#pragma unroll
    for(int qq=0;qq<8;qq++) px += __shfl(t2, lr*8+qq) * DT.d[qq][lc];
    po[(size_t)lr*HW + lc] = (float)px;
  }
}

// ---------------- host launch ----------------
extern "C" void kernel_launch(void* const* d_in, const int* in_sizes, int n_in,
                              void* d_out, int out_size, void* d_ws, size_t ws_size,
                              hipStream_t stream) {
  const float* cover  = (const float*)d_in[0];
  const int*   secret = (const int*)d_in[1];
  float* out = (float*)d_out;
  char*  ws  = (char*)d_ws;

  // ws layout (bytes)
  double*   var      = (double*)(ws);             // 98304*8 = 786432
  unsigned* bins     = (unsigned*)(ws + 786432);  // 8192*4  -> 819200
  unsigned* cand_cnt = (unsigned*)(ws + 819200);  // 4 (pad)  -> 819208
  int*      desc     = (int*)(ws + 819208);       // 3 ints (pad to 24) -> 819232
  ull*      cand     = (ull*)(ws + 819232);       // 2048*8  -> 835616

  k_stats <<<NWG,       256,  0, stream>>>(cover, out, var, bins, cand_cnt);
  k_hist  <<<NBLK/1024, 1024, 0, stream>>>(var, bins);
  k_gather<<<NBLK/1024, 1024, 0, stream>>>(var, bins, cand_cnt, cand, desc);
  k_final <<<1,         1024, 0, stream>>>(cover, secret, var, desc, cand_cnt, cand, out);
}